// Round 2
// baseline (278.554 us; speedup 1.0000x reference)
//
#include <hip/hip_runtime.h>

// ---------------------------------------------------------------------------
// LengthRegulator — R7 DIAGNOSTIC round (code identical to R6 gather).
//
// Observation: scatter (R5, 231 µs) and gather (R6, 239 µs) — two radically
// different formulations — differ by only 8 µs, and neither kernel appears
// in the rocprof top-5 (all slots are the harness's 126 µs poison-fills).
// So dur_us contains a large fixed harness component and an unknown kernel
// component (< 126 µs). This round launches the idempotent gather TWICE:
//   dur_us(R7) - dur_us(R6) == true gather cost, measured in situ.
// If the delta is ~40 µs, the gather is at its ~37 µs traffic floor
// (195 MB write + ~40 MB read @ 6.3 TB/s) and the session is done.
// If the delta is ~100 µs, next round attacks the gather with full force.
// ---------------------------------------------------------------------------

#define LR_T 512  // tokens per row (fixed by setup_inputs)
#define FPB  64   // output frames per block

typedef float vfloat4 __attribute__((ext_vector_type(4)));

__global__ void lr_cumsum_kernel(const int* __restrict__ dur,
                                 int* __restrict__ cum, int T) {
    __shared__ int s[LR_T];
    const int b = blockIdx.x;
    const int tid = threadIdx.x;
    int v = dur[(size_t)b * T + tid];
    v = v > 0 ? v : 0;  // jnp.maximum(dur, 0)
    s[tid] = v;
    __syncthreads();
    for (int off = 1; off < LR_T; off <<= 1) {
        int add = (tid >= off) ? s[tid - off] : 0;
        __syncthreads();
        s[tid] += add;
        __syncthreads();
    }
    cum[(size_t)b * T + tid] = s[tid];
}

__global__ void __launch_bounds__(256)
lr_gather_kernel(const vfloat4* __restrict__ x4,
                 const int* __restrict__ cum,
                 vfloat4* __restrict__ out4,
                 int T_out) {
    __shared__ int s_cum[LR_T];
    __shared__ int s_idx[FPB];
    const int tid = threadIdx.x;   // 0..255
    const int b   = blockIdx.y;    // batch row
    const int t0  = blockIdx.x * FPB;

    // Stage this row's cumsum in LDS: 512 ints, two coalesced loads.
    const int* crow = cum + (size_t)b * LR_T;
    s_cum[tid]       = crow[tid];
    s_cum[tid + 256] = crow[tid + 256];
    __syncthreads();

    const int nf = min(FPB, T_out - t0);

    // Branchless rank search: pos = count of cum[j] <= t, saturating at
    // LR_T-1 (sum of steps = 511), which IS the reference's min(idx, T-1).
    if (tid < nf) {
        const int t = t0 + tid;
        int pos = 0;
        #pragma unroll
        for (int s = LR_T / 2; s > 0; s >>= 1)
            pos += (s_cum[pos + s - 1] <= t) ? s : 0;
        s_idx[tid] = pos;
    }
    __syncthreads();

    // 2 output frames per iteration: 128 lanes x 16 B = one 2 KB row each.
    const int lane = tid & 127;    // float4 lane within a C=512 row
    const int half = tid >> 7;     // which frame of the pair
    const vfloat4* __restrict__ xrow = x4 + (size_t)b * LR_T * 128 + lane;
    vfloat4* __restrict__ obase = out4 + ((size_t)b * T_out + t0) * 128 + lane;
    #pragma unroll 4
    for (int f = half; f < nf; f += 2) {
        const vfloat4 v = xrow[(size_t)s_idx[f] * 128];
        __builtin_nontemporal_store(v, obase + (size_t)f * 128);
    }
}

extern "C" void kernel_launch(void* const* d_in, const int* in_sizes, int n_in,
                              void* d_out, int out_size, void* d_ws, size_t ws_size,
                              hipStream_t stream) {
    const float* x   = (const float*)d_in[0];
    const int*   dur = (const int*)d_in[1];
    float*       out = (float*)d_out;

    const int B  = 32;
    const int BT = in_sizes[1];            // B*T
    const int T  = BT / B;                 // 512
    const int C  = in_sizes[0] / BT;       // 512 (row = 128 float4)
    const int T_out = out_size / (B * C);  // data-dependent, encoded in out_size

    int* cum = (int*)d_ws;                 // B*T ints = 64 KB scratch

    lr_cumsum_kernel<<<B, T, 0, stream>>>(dur, cum, T);

    if (T_out > 0) {
        dim3 grid((T_out + FPB - 1) / FPB, B);
        // DIAGNOSTIC: launch the idempotent gather twice; the marginal
        // dur_us vs R6 is the gather's true in-situ cost.
        for (int rep = 0; rep < 2; ++rep) {
            lr_gather_kernel<<<grid, 256, 0, stream>>>(
                (const vfloat4*)x, cum, (vfloat4*)out, T_out);
        }
    }
}

// Round 3
// 229.685 us; speedup vs baseline: 1.2128x; 1.2128x over previous
//
#include <hip/hip_runtime.h>

// ---------------------------------------------------------------------------
// LengthRegulator (scatter formulation — measured-best, FINAL):
//   x   [B, T, C]  float32
//   dur [B, T]     int32
//   out [B, T_out, C]; out[b,t,:] = x[b, idx, :],
//     idx = upper_bound(cumsum(max(dur,0))[b,:], t) clamped to T-1.
//   T_out recovered from out_size: T_out = out_size / (B*C).
//
// Kernel 1: per-row inclusive cumsum of dur -> cum (B*T ints in d_ws).
// Kernel 2: one 256-thread block per source token (b,j): reads its 2 KB row
//   of x ONCE (nontemporal), writes it into out rows [cum[j-1], cum[j]) two
//   rows per iteration with nontemporal stores. Clamp tail [cum[T-1], T_out)
//   split across NTAIL blocks per batch row.
//
// SESSION CLOSE-OUT (R0-R7 measured decomposition):
//   dur_us(total) ~= 200 us fixed harness (811 MB poison-fill @6.4 TB/s =
//   126 us + reset/launch machinery; unreachable from kernel_launch)
//   + ~2 us cumsum + ~31 us scatter. Double-launch diagnostic (R7) measured
//   the alternative gather formulation at 39.3 us marginal; scatter infers
//   to ~31 us vs a ~35 us naive traffic floor (195 MB NT-write + 33.5 MB
//   NT-read @ 6.4 TB/s measured ceiling) — i.e. the kernel component is AT
//   the memory roofline. Tuning history: 128thr 1-row = 246 us total;
//   256thr 2-row NT = 231.2 us (best); 512thr 4-row NT = 237.5 us;
//   gather 64-frame blocks = 239.3 us.
// ---------------------------------------------------------------------------

#define LR_T   512  // tokens per row (fixed by setup_inputs)
#define NTAIL  64   // blocks per batch row for the clamp tail

// clang vector type: __builtin_nontemporal_* accepts vectors of float,
// but NOT HIP's struct-based float4.
typedef float vfloat4 __attribute__((ext_vector_type(4)));

__global__ void lr_cumsum_kernel(const int* __restrict__ dur,
                                 int* __restrict__ cum, int T) {
    __shared__ int s[LR_T];
    const int b = blockIdx.x;
    const int tid = threadIdx.x;
    int v = dur[(size_t)b * T + tid];
    v = v > 0 ? v : 0;  // jnp.maximum(dur, 0)
    s[tid] = v;
    __syncthreads();
    for (int off = 1; off < LR_T; off <<= 1) {
        int add = (tid >= off) ? s[tid - off] : 0;
        __syncthreads();
        s[tid] += add;
        __syncthreads();
    }
    cum[(size_t)b * T + tid] = s[tid];
}

__global__ void __launch_bounds__(256)
lr_scatter_kernel(const vfloat4* __restrict__ x4,
                  const int* __restrict__ cum,
                  vfloat4* __restrict__ out4,
                  int T, int T_out) {
    const int jj   = blockIdx.x;     // source token, or T..T+NTAIL-1 for tail
    const int b    = blockIdx.y;     // batch row
    const int tid  = threadIdx.x;    // 0..255
    const int lane = tid & 127;      // float4 lane within a C=512 row
    const int half = tid >> 7;       // which row of the pair this thread writes

    const int* crow = cum + (size_t)b * T;
    int j, start, end;
    if (jj < T) {
        j = jj;
        if (jj > 0) {
            // one 8 B load for both span boundaries
            const int2 se = *(const int2*)(crow + jj - 1);
            start = se.x;
            end   = se.y;
        } else {
            start = 0;
            end   = crow[0];
        }
    } else {
        // Clamp tail: frames [crow[T-1], T_out) all replicate row T-1.
        j = T - 1;
        const int tstart = crow[T - 1];
        const int tlen   = T_out - tstart;
        if (tlen <= 0) return;
        const int chunk = (tlen + NTAIL - 1) / NTAIL;
        const int k     = jj - T;
        start = tstart + k * chunk;
        end   = start + chunk;
        if (end > T_out) end = T_out;
    }
    if (start >= end) return;  // dur == 0, or empty tail slice

    // Read this token's row once: 128 lanes x 16 B = 2 KB (streamed).
    const vfloat4 val =
        __builtin_nontemporal_load(&x4[((size_t)b * T + j) * 128 + lane]);

    // Two output rows per iteration, nontemporal streaming stores.
    vfloat4* const base = out4 + (size_t)b * T_out * 128 + lane;
    vfloat4* dst = base + ((size_t)start + half) * 128;
    for (int t = start + half; t < end; t += 2) {
        __builtin_nontemporal_store(val, dst);
        dst += 256;
    }
}

extern "C" void kernel_launch(void* const* d_in, const int* in_sizes, int n_in,
                              void* d_out, int out_size, void* d_ws, size_t ws_size,
                              hipStream_t stream) {
    const float* x   = (const float*)d_in[0];
    const int*   dur = (const int*)d_in[1];
    float*       out = (float*)d_out;

    const int B  = 32;
    const int BT = in_sizes[1];            // B*T
    const int T  = BT / B;                 // 512
    const int C  = in_sizes[0] / BT;       // 512 (row = 128 float4)
    const int T_out = out_size / (B * C);  // data-dependent, encoded in out_size

    int* cum = (int*)d_ws;                 // B*T ints = 64 KB scratch

    lr_cumsum_kernel<<<B, T, 0, stream>>>(dur, cum, T);

    dim3 grid(T + NTAIL, B);               // source tokens + tail slices
    lr_scatter_kernel<<<grid, 256, 0, stream>>>(
        (const vfloat4*)x, cum, (vfloat4*)out, T, T_out);
}